// Round 2
// baseline (196.786 us; speedup 1.0000x reference)
//
#include <hip/hip_runtime.h>
#include <hip/hip_bf16.h>

typedef __bf16 bf16x8 __attribute__((ext_vector_type(8)));
typedef float floatx4 __attribute__((ext_vector_type(4)));

__device__ __forceinline__ unsigned short f2bf(float f) {
  __bf16 b = (__bf16)f;
  return __builtin_bit_cast(unsigned short, b);
}

// ---------------------------------------------------------------------------
// Kernel 1: decode w1 bits -> bf16 {-1,0,+1} in MFMA-FRAGMENT-TRANSPOSED order:
//   w1t[((kc*4 + quad)*256 + row)*8 + k]  holds W[row][kc*32 + quad*8 + k]
// (kc in 0..24, K padded 784->800 with zeros). With sec = kc*4+quad = byte
// index j, thread t = sec*256 + row writes 16 consecutive bytes at w1t + t*8:
// perfectly coalesced stores, and the fused kernel's B-fragment loads become
// contiguous 256B runs per quad.
// ---------------------------------------------------------------------------
__global__ void decode_w1_kernel(const int* __restrict__ w1p,
                                 const int* __restrict__ m1p,
                                 unsigned short* __restrict__ w1t) {
  int t = blockIdx.x * 256 + threadIdx.x;   // [0, 25600)
  int r = t & 255;                          // row 0..255
  int j = t >> 8;                           // byte group 0..99 (= kc*4+quad)
  unsigned short vals[8];
#pragma unroll
  for (int k = 0; k < 8; ++k) vals[k] = 0;
  if (j < 98) {
    unsigned int v = (unsigned int)w1p[r * 98 + j];
    unsigned int m = (unsigned int)m1p[r * 98 + j];
#pragma unroll
    for (int k = 0; k < 8; ++k) {           // MSB-first per byte (matches _unpack)
      unsigned int bit = (v >> (7 - k)) & 1u;
      unsigned int mk  = (m >> (7 - k)) & 1u;
      vals[k] = (unsigned short)(mk ? (bit ? 0x3F80u : 0xBF80u) : 0u);  // +1/-1/0
    }
  }
  uint4 pack;
  pack.x = (unsigned)vals[0] | ((unsigned)vals[1] << 16);
  pack.y = (unsigned)vals[2] | ((unsigned)vals[3] << 16);
  pack.z = (unsigned)vals[4] | ((unsigned)vals[5] << 16);
  pack.w = (unsigned)vals[6] | ((unsigned)vals[7] << 16);
  *reinterpret_cast<uint4*>(w1t + t * 8) = pack;
}

// ---------------------------------------------------------------------------
// Kernel 2: fused  h = relu(a1 * x@W1^T);  out = a2 * (h@W2^T)
// v3: BARRIER-FREE K-loop. No LDS in phase 1: W fragments load straight from
// the pre-transposed w1t into VGPRs (coalesced dwordx4); x fragments load
// per-wave from global and convert in-register (4x intra-block re-read is
// absorbed by L1 -- all 4 waves touch the same 8KB chunk concurrently).
// The compiler is free to pipeline the 12 loads/chunk across iterations.
// LDS + the single __syncthreads are only for the phase-2 H/W2 exchange.
//   A-frag: A[m=lane&15][k=quad*8+j]; B-frag: B^T[n=lane&15][k=quad*8+j];
//   C/D: col=lane&15, row=quad*4+reg  (m89-verified layouts).
// ---------------------------------------------------------------------------
#define BM 64
#define NCH 25
#define HS_LD 264   // 256 + 8 pad: keeps layer-2 frag reads ~conflict-free

#define OFF_HS  0
#define OFF_W2  16896

__global__ __launch_bounds__(256, 3) void fused_kernel(
    const float* __restrict__ x,
    const unsigned short* __restrict__ w1t,
    const int* __restrict__ w2p,
    const int* __restrict__ m2p,
    const float* __restrict__ a1p,
    const float* __restrict__ a2p,
    float* __restrict__ out) {
  __shared__ unsigned short smem[64 * HS_LD + 16 * 256];  // 41984 B (phase 2 only)

  const int tid  = threadIdx.x;
  const int wave = tid >> 6;
  const int lane = tid & 63;
  const int l15  = lane & 15;
  const int quad = lane >> 4;
  const int row0 = blockIdx.x * BM;

  floatx4 acc[4][4];
#pragma unroll
  for (int i = 0; i < 4; ++i)
#pragma unroll
    for (int j = 0; j < 4; ++j) acc[i][j] = (floatx4){0.f, 0.f, 0.f, 0.f};

  // Per-lane base pointers (invariant across the K-loop).
  const float* xl = x + (size_t)row0 * 784 + (size_t)l15 * 784 + quad * 8;
  const unsigned short* wl = w1t + ((size_t)quad * 256 + wave * 64 + l15) * 8;

  // One K-chunk: 8 x-loads + 4 W-loads (all independent), 32 cvt, 16 MFMA.
  auto do_chunk = [&](int kc, bool full) {
    float4 xa[4], xb[4];
    const float* xp = xl + kc * 32;
#pragma unroll
    for (int mi = 0; mi < 4; ++mi) {
      if (full || quad < 2) {
        xa[mi] = *reinterpret_cast<const float4*>(xp + mi * 16 * 784);
        xb[mi] = *reinterpret_cast<const float4*>(xp + mi * 16 * 784 + 4);
      } else {  // tail chunk, cols 784..799 are zero-pad
        xa[mi] = (float4){0.f, 0.f, 0.f, 0.f};
        xb[mi] = (float4){0.f, 0.f, 0.f, 0.f};
      }
    }
    bf16x8 bfr[4];
    const unsigned short* wp = wl + (size_t)kc * 4 * 256 * 8;
#pragma unroll
    for (int nj = 0; nj < 4; ++nj)
      bfr[nj] = *reinterpret_cast<const bf16x8*>(wp + nj * 16 * 8);
    bf16x8 af[4];
#pragma unroll
    for (int mi = 0; mi < 4; ++mi) {
      af[mi][0] = (__bf16)xa[mi].x; af[mi][1] = (__bf16)xa[mi].y;
      af[mi][2] = (__bf16)xa[mi].z; af[mi][3] = (__bf16)xa[mi].w;
      af[mi][4] = (__bf16)xb[mi].x; af[mi][5] = (__bf16)xb[mi].y;
      af[mi][6] = (__bf16)xb[mi].z; af[mi][7] = (__bf16)xb[mi].w;
    }
#pragma unroll
    for (int mi = 0; mi < 4; ++mi)
#pragma unroll
      for (int nj = 0; nj < 4; ++nj)
        acc[mi][nj] = __builtin_amdgcn_mfma_f32_16x16x32_bf16(
            af[mi], bfr[nj], acc[mi][nj], 0, 0, 0);
  };

#pragma unroll 2
  for (int kc = 0; kc < NCH - 1; ++kc) do_chunk(kc, true);
  do_chunk(NCH - 1, false);   // cols 768..783 valid (quads 0,1), 784..799 pad

  // ---- epilogue layer 1: h = relu(a1*acc) -> Hs bf16 ----
  const float a1 = a1p[0];
  const float a2 = a2p[0];
#pragma unroll
  for (int mi = 0; mi < 4; ++mi) {
#pragma unroll
    for (int nj = 0; nj < 4; ++nj) {
      int col   = wave * 64 + nj * 16 + l15;
      int rbase = mi * 16 + quad * 4;
#pragma unroll
      for (int r = 0; r < 4; ++r) {
        float h = fmaxf(a1 * acc[mi][nj][r], 0.f);
        smem[OFF_HS + (rbase + r) * HS_LD + col] = f2bf(h);
      }
    }
  }
  // ---- decode w2 -> W2s[16][256] (rows 10..15 zero) ----
#pragma unroll
  for (int it = 0; it < 2; ++it) {
    int idx = it * 256 + tid;
    if (idx < 320) {
      int r = idx >> 5, j = idx & 31;
      unsigned int v = (unsigned int)w2p[r * 32 + j];
      unsigned int m = (unsigned int)m2p[r * 32 + j];
#pragma unroll
      for (int k = 0; k < 8; ++k) {
        unsigned int bit = (v >> (7 - k)) & 1u;
        unsigned int mk  = (m >> (7 - k)) & 1u;
        smem[OFF_W2 + r * 256 + j * 8 + k] =
            (unsigned short)(mk ? (bit ? 0x3F80u : 0xBF80u) : 0u);
      }
    }
  }
#pragma unroll
  for (int r = 10; r < 16; ++r) smem[OFF_W2 + r * 256 + tid] = 0;
  __syncthreads();   // the ONLY barrier in the kernel

  // ---- layer 2: out[64][10] = Hs @ W2s^T; wave handles 16 rows, K=256 ----
  floatx4 o2 = (floatx4){0.f, 0.f, 0.f, 0.f};
#pragma unroll
  for (int ks = 0; ks < 8; ++ks) {
    bf16x8 ha = *reinterpret_cast<const bf16x8*>(
        &smem[OFF_HS + (wave * 16 + l15) * HS_LD + ks * 32 + quad * 8]);
    bf16x8 wb = *reinterpret_cast<const bf16x8*>(
        &smem[OFF_W2 + l15 * 256 + ks * 32 + quad * 8]);
    o2 = __builtin_amdgcn_mfma_f32_16x16x32_bf16(ha, wb, o2, 0, 0, 0);
  }
  if (l15 < 10) {
#pragma unroll
    for (int r = 0; r < 4; ++r) {
      int gr = row0 + wave * 16 + quad * 4 + r;
      out[(size_t)gr * 10 + l15] = a2 * o2[r];
    }
  }
}

extern "C" void kernel_launch(void* const* d_in, const int* in_sizes, int n_in,
                              void* d_out, int out_size, void* d_ws, size_t ws_size,
                              hipStream_t stream) {
  const float* x   = (const float*)d_in[0];
  const int*   w1p = (const int*)d_in[1];
  const int*   m1p = (const int*)d_in[2];
  const float* a1  = (const float*)d_in[3];
  const int*   w2p = (const int*)d_in[4];
  const int*   m2p = (const int*)d_in[5];
  const float* a2  = (const float*)d_in[6];
  unsigned short* w1t = (unsigned short*)d_ws;  // 256*800 bf16 = 400 KB scratch
  float* out = (float*)d_out;

  decode_w1_kernel<<<100, 256, 0, stream>>>(w1p, m1p, w1t);
  fused_kernel<<<512, 256, 0, stream>>>(x, w1t, w2p, m2p, a1, a2, out);
}

// Round 3
// 171.721 us; speedup vs baseline: 1.1460x; 1.1460x over previous
//
#include <hip/hip_runtime.h>
#include <hip/hip_bf16.h>

typedef __bf16 bf16x8 __attribute__((ext_vector_type(8)));
typedef float floatx4 __attribute__((ext_vector_type(4)));

#define GLB_AS __attribute__((address_space(1)))
#define LDS_AS __attribute__((address_space(3)))

__device__ __forceinline__ void async_cp16(const void* g, void* l) {
  // 16B-per-lane direct global->LDS copy (global_load_lds_dwordx4).
  // LDS dest must be wave-uniform base + lane*16 -- seg layouts guarantee it.
  __builtin_amdgcn_global_load_lds((GLB_AS void*)g, (LDS_AS void*)l, 16, 0, 0);
}

__device__ __forceinline__ unsigned short f2bf(float f) {
  __bf16 b = (__bf16)f;
  return __builtin_bit_cast(unsigned short, b);
}

// ---------------------------------------------------------------------------
// Kernel 1: decode w1 bits -> bf16 {-1,0,+1} in MFMA-FRAGMENT-TRANSPOSED order:
//   w1t[((kc*4 + quad)*256 + row)*8 + k]  holds W[row][kc*32 + quad*8 + k]
// (kc in 0..24, K padded 784->800 with zeros). Each K-chunk kc is a CONTIGUOUS
// 16KB slab of w1t -> the fused kernel stages it with linear global_load_lds
// and the B-fragment LDS reads are conflict-free (16 lanes = 256 contiguous B).
// ---------------------------------------------------------------------------
__global__ void decode_w1_kernel(const int* __restrict__ w1p,
                                 const int* __restrict__ m1p,
                                 unsigned short* __restrict__ w1t) {
  int t = blockIdx.x * 256 + threadIdx.x;   // [0, 25600)
  int r = t & 255;                          // row 0..255
  int j = t >> 8;                           // byte group 0..99 (= kc*4+quad)
  unsigned short vals[8];
#pragma unroll
  for (int k = 0; k < 8; ++k) vals[k] = 0;
  if (j < 98) {
    unsigned int v = (unsigned int)w1p[r * 98 + j];
    unsigned int m = (unsigned int)m1p[r * 98 + j];
#pragma unroll
    for (int k = 0; k < 8; ++k) {           // MSB-first per byte (matches _unpack)
      unsigned int bit = (v >> (7 - k)) & 1u;
      unsigned int mk  = (m >> (7 - k)) & 1u;
      vals[k] = (unsigned short)(mk ? (bit ? 0x3F80u : 0xBF80u) : 0u);  // +1/-1/0
    }
  }
  uint4 pack;
  pack.x = (unsigned)vals[0] | ((unsigned)vals[1] << 16);
  pack.y = (unsigned)vals[2] | ((unsigned)vals[3] << 16);
  pack.z = (unsigned)vals[4] | ((unsigned)vals[5] << 16);
  pack.w = (unsigned)vals[6] | ((unsigned)vals[7] << 16);
  *reinterpret_cast<uint4*>(w1t + t * 8) = pack;
}

// ---------------------------------------------------------------------------
// Kernel 2: fused  h = relu(a1 * x@W1^T);  out = a2 * (h@W2^T)
// v4: 512 threads (8 waves) per block, BM=64, grid=512 -> 16 waves/CU (2x v2).
// v2-style double-buffered one-barrier pipeline; W staged via global_load_lds
// from the fragment-transposed w1t (contiguous chunk, conflict-free reads);
// X staged fragment-major through VGPR cvt (conflict-free A-frag reads).
// Wave w computes 64 rows x 32 cols (cols w*32..w*32+31): acc[4][2].
//   A-frag: A[m=l15][k=quad*8+j]; B-frag: B^T[n=l15][k=quad*8+j];
//   C/D: col=l15, row=quad*4+reg  (m89-verified layouts).
// ---------------------------------------------------------------------------
#define BM 64
#define BK 32
#define NCH 25
#define HS_LD 264   // 256 + 8 pad: layer-2 Hs reads conflict-free
#define W2_LD 264   // same pad for W2s (was 16-way conflicted at 256)

// phase-1 LDS layout (shorts), double-buffered, fragment-major:
//   Ws0[1024][8] @ 0      Ws1[1024][8] @ 8192      (each 16KB)
//   Xs0[ 256][8] @ 16384  Xs1[ 256][8] @ 18432     (each 4KB; [quad*64+row][8])
// phase-2 layout (shorts):
//   Hs[64][264] @ 0 .. 16895,  W2s[16][264] @ 16896 .. 21119
#define OFF_WS0 0
#define OFF_WS1 8192
#define OFF_XS0 16384
#define OFF_XS1 18432
#define OFF_HS  0
#define OFF_W2  16896

__global__ __launch_bounds__(512, 4) void fused_kernel(
    const float* __restrict__ x,
    const unsigned short* __restrict__ w1t,
    const int* __restrict__ w2p,
    const int* __restrict__ m2p,
    const float* __restrict__ a1p,
    const float* __restrict__ a2p,
    float* __restrict__ out) {
  __shared__ unsigned short smem[64 * HS_LD + 16 * W2_LD];  // 42240 B

  const int tid  = threadIdx.x;
  const int wave = tid >> 6;
  const int lane = tid & 63;
  const int l15  = lane & 15;
  const int quad = lane >> 4;
  const int row0 = blockIdx.x * BM;

  floatx4 acc[4][2];
#pragma unroll
  for (int i = 0; i < 4; ++i)
#pragma unroll
    for (int j = 0; j < 2; ++j) acc[i][j] = (floatx4){0.f, 0.f, 0.f, 0.f};

  // Per-thread x staging coords: one float4 per thread per chunk.
  const int xr  = tid >> 3;        // row 0..63
  const int xc4 = tid & 7;         // col group (4 floats each)
  const int xq  = xc4 >> 1;        // k-quad
  const int xh  = xc4 & 1;         // half within quad (4 shorts)
  const float* xbase = x + (size_t)(row0 + xr) * 784 + xc4 * 4;
  const int xs_off = (xq * 64 + xr) * 8 + xh * 4;   // shorts, frag-major

  auto stage_w = [&](int kc, int offW) {
#pragma unroll
    for (int it = 0; it < 2; ++it) {
      int seg = it * 512 + tid;              // [0,1024); 16B per seg
      async_cp16(w1t + (size_t)kc * 8192 + seg * 8, &smem[offW + seg * 8]);
    }
  };
  auto load_x = [&](int kc, float4& xv) {
    int col = kc * BK + xc4 * 4;
    if (col < 784) {
      xv = *reinterpret_cast<const float4*>(xbase + kc * BK);
    } else {
      xv = (float4){0.f, 0.f, 0.f, 0.f};     // K pad 784..799
    }
  };
  auto cvt_write = [&](int offX, const float4& xv) {
    ushort4 b;
    b.x = f2bf(xv.x); b.y = f2bf(xv.y); b.z = f2bf(xv.z); b.w = f2bf(xv.w);
    *reinterpret_cast<ushort4*>(&smem[offX + xs_off]) = b;
  };
  auto compute = [&](int offW, int offX) {
    bf16x8 af[4], bfr[2];
#pragma unroll
    for (int mi = 0; mi < 4; ++mi)
      af[mi] = *reinterpret_cast<const bf16x8*>(
          &smem[offX + (quad * 64 + mi * 16 + l15) * 8]);
#pragma unroll
    for (int nj = 0; nj < 2; ++nj)
      bfr[nj] = *reinterpret_cast<const bf16x8*>(
          &smem[offW + (quad * 256 + wave * 32 + nj * 16 + l15) * 8]);
#pragma unroll
    for (int mi = 0; mi < 4; ++mi)
#pragma unroll
      for (int nj = 0; nj < 2; ++nj)
        acc[mi][nj] = __builtin_amdgcn_mfma_f32_16x16x32_bf16(
            af[mi], bfr[nj], acc[mi][nj], 0, 0, 0);
  };

  // --- prologue: stage chunk 0 into buffer 0 ---
  {
    float4 xv;
    load_x(0, xv);
    stage_w(0, OFF_WS0);
    cvt_write(OFF_XS0, xv);
  }
  __syncthreads();

  // --- main loop: prefetch(t+1) || compute(t); ONE barrier per chunk ---
#pragma unroll 2
  for (int kc = 0; kc < NCH - 1; ++kc) {
    const int p = kc & 1;
    float4 xn;
    load_x(kc + 1, xn);                        // x loads first
    stage_w(kc + 1, p ? OFF_WS0 : OFF_WS1);    // async W->LDS (stay in flight)
    compute(p ? OFF_WS1 : OFF_WS0,             // MFMA on current buffer
            p ? OFF_XS1 : OFF_XS0);
    cvt_write(p ? OFF_XS0 : OFF_XS1, xn);      // waits x only; W still in flight
    __syncthreads();                           // drain + swap
  }
  compute(OFF_WS0, OFF_XS0);                   // chunk 24 (staged by kc=23)
  __syncthreads();

  // ---- epilogue layer 1: h = relu(a1*acc) -> Hs bf16 ----
  const float a1 = a1p[0];
  const float a2 = a2p[0];
#pragma unroll
  for (int mi = 0; mi < 4; ++mi) {
#pragma unroll
    for (int nj = 0; nj < 2; ++nj) {
      int col   = wave * 32 + nj * 16 + l15;
      int rbase = mi * 16 + quad * 4;
#pragma unroll
      for (int r = 0; r < 4; ++r) {
        float h = fmaxf(a1 * acc[mi][nj][r], 0.f);
        smem[OFF_HS + (rbase + r) * HS_LD + col] = f2bf(h);
      }
    }
  }
  // ---- decode w2 -> W2s[16][264] (rows 10..15 zero) ----
  if (tid < 320) {
    int r = tid >> 5, j = tid & 31;
    unsigned int v = (unsigned int)w2p[r * 32 + j];
    unsigned int m = (unsigned int)m2p[r * 32 + j];
#pragma unroll
    for (int k = 0; k < 8; ++k) {
      unsigned int bit = (v >> (7 - k)) & 1u;
      unsigned int mk  = (m >> (7 - k)) & 1u;
      smem[OFF_W2 + r * W2_LD + j * 8 + k] =
          (unsigned short)(mk ? (bit ? 0x3F80u : 0xBF80u) : 0u);
    }
  }
  // zero rows 10..15 of W2s (cols 0..255 read by layer 2)
  for (int idx = tid; idx < 6 * 256; idx += 512) {
    int r = 10 + (idx >> 8), c = idx & 255;
    smem[OFF_W2 + r * W2_LD + c] = 0;
  }
  __syncthreads();   // the ONLY barrier between phases

  // ---- layer 2: out[64][10] = Hs @ W2s^T; waves 0..3, 16 rows each, K=256 ----
  if (wave < 4) {
    floatx4 o2 = (floatx4){0.f, 0.f, 0.f, 0.f};
#pragma unroll
    for (int ks = 0; ks < 8; ++ks) {
      bf16x8 ha = *reinterpret_cast<const bf16x8*>(
          &smem[OFF_HS + (wave * 16 + l15) * HS_LD + ks * 32 + quad * 8]);
      bf16x8 wb = *reinterpret_cast<const bf16x8*>(
          &smem[OFF_W2 + l15 * W2_LD + ks * 32 + quad * 8]);
      o2 = __builtin_amdgcn_mfma_f32_16x16x32_bf16(ha, wb, o2, 0, 0, 0);
    }
    if (l15 < 10) {
#pragma unroll
      for (int r = 0; r < 4; ++r) {
        int gr = row0 + wave * 16 + quad * 4 + r;
        out[(size_t)gr * 10 + l15] = a2 * o2[r];
      }
    }
  }
}

extern "C" void kernel_launch(void* const* d_in, const int* in_sizes, int n_in,
                              void* d_out, int out_size, void* d_ws, size_t ws_size,
                              hipStream_t stream) {
  const float* x   = (const float*)d_in[0];
  const int*   w1p = (const int*)d_in[1];
  const int*   m1p = (const int*)d_in[2];
  const float* a1  = (const float*)d_in[3];
  const int*   w2p = (const int*)d_in[4];
  const int*   m2p = (const int*)d_in[5];
  const float* a2  = (const float*)d_in[6];
  unsigned short* w1t = (unsigned short*)d_ws;  // 256*800 bf16 = 400 KB scratch
  float* out = (float*)d_out;

  decode_w1_kernel<<<100, 256, 0, stream>>>(w1p, m1p, w1t);
  fused_kernel<<<512, 512, 0, stream>>>(x, w1t, w2p, m2p, a1, a2, out);
}

// Round 4
// 170.880 us; speedup vs baseline: 1.1516x; 1.0049x over previous
//
#include <hip/hip_runtime.h>
#include <hip/hip_bf16.h>

typedef __bf16 bf16x8 __attribute__((ext_vector_type(8)));
typedef float floatx4 __attribute__((ext_vector_type(4)));

__device__ __forceinline__ unsigned short f2bf(float f) {
  __bf16 b = (__bf16)f;
  return __builtin_bit_cast(unsigned short, b);
}

// ---------------------------------------------------------------------------
// Kernel 1: decode w1 bits -> bf16 {-1,0,+1} in MFMA-FRAGMENT-TRANSPOSED order:
//   w1t[(kq*256 + row)*8 + k]  holds W[row][kq*8 + k],  kq in [0,104)
// (K padded 784 -> 832 with zeros: kq 98..103 all-zero so the fused K-loop is
// 26 uniform chunks of 32). Fragment rows for one (chunk, quad, wave) are 16
// consecutive rows = 256 contiguous bytes -> direct-to-VGPR loads coalesce.
// ---------------------------------------------------------------------------
__global__ void decode_w1_kernel(const int* __restrict__ w1p,
                                 const int* __restrict__ m1p,
                                 unsigned short* __restrict__ w1t) {
  int t = blockIdx.x * 256 + threadIdx.x;   // [0, 104*256)
  int r = t & 255;                          // row 0..255
  int j = t >> 8;                           // byte group (kq) 0..103
  unsigned short vals[8];
#pragma unroll
  for (int k = 0; k < 8; ++k) vals[k] = 0;
  if (j < 98) {
    unsigned int v = (unsigned int)w1p[r * 98 + j];
    unsigned int m = (unsigned int)m1p[r * 98 + j];
#pragma unroll
    for (int k = 0; k < 8; ++k) {           // MSB-first per byte (matches _unpack)
      unsigned int bit = (v >> (7 - k)) & 1u;
      unsigned int mk  = (m >> (7 - k)) & 1u;
      vals[k] = (unsigned short)(mk ? (bit ? 0x3F80u : 0xBF80u) : 0u);  // +1/-1/0
    }
  }
  uint4 pack;
  pack.x = (unsigned)vals[0] | ((unsigned)vals[1] << 16);
  pack.y = (unsigned)vals[2] | ((unsigned)vals[3] << 16);
  pack.z = (unsigned)vals[4] | ((unsigned)vals[5] << 16);
  pack.w = (unsigned)vals[6] | ((unsigned)vals[7] << 16);
  *reinterpret_cast<uint4*>(w1t + t * 8) = pack;
}

// ---------------------------------------------------------------------------
// Kernel 2: fused  h = relu(a1 * x@W1^T);  out = a2 * (h@W2^T)
// v5: BARRIER-FREE K-loop (5 barriers in the whole kernel).
//  - X staged to LDS ONCE per super-phase (2 phases x 416 cols, frag-major
//    [kq][64][8] bf16): x HBM cost paid as one deep-queued burst.
//  - W: wave-private fragments loaded straight from w1t to VGPRs (contiguous,
//    L2-hot), ping-pong prefetched one chunk ahead. No LDS, no barrier.
//  - 512 thr (8 waves) / block, BM=64, grid=512 -> 2 blocks/CU co-resident.
//   A-frag: A[m=l15][k=quad*8+j]; B-frag: B^T[n=l15][k=quad*8+j];
//   C/D: col=l15, row=quad*4+reg  (m89-verified layouts).
// ---------------------------------------------------------------------------
#define BM 64
#define NCHG 26      // global chunks of 32 cols (832 = 26*32)
#define NCHP 13      // chunks per super-phase (416 cols)
#define HS_LD 264    // 256 + 8 pad: layer-2 Hs reads conflict-free
#define W2_LD 264

// phase-1 LDS (shorts): Xs[52][64][8] = 26624 shorts = 53248 B
// phase-2 overlay:      Hs[64][264] @ 0,  W2s[16][264] @ 16896 (end 21120)
#define OFF_W2 16896

__global__ __launch_bounds__(512, 4) void fused_kernel(
    const float* __restrict__ x,
    const unsigned short* __restrict__ w1t,
    const int* __restrict__ w2p,
    const int* __restrict__ m2p,
    const float* __restrict__ a1p,
    const float* __restrict__ a2p,
    float* __restrict__ out) {
  __shared__ unsigned short smem[26624];   // 53248 B

  const int tid  = threadIdx.x;
  const int wave = tid >> 6;
  const int lane = tid & 63;
  const int l15  = lane & 15;
  const int quad = lane >> 4;
  const int row0 = blockIdx.x * BM;

  floatx4 acc[4][2];
#pragma unroll
  for (int i = 0; i < 4; ++i)
#pragma unroll
    for (int j = 0; j < 2; ++j) acc[i][j] = (floatx4){0.f, 0.f, 0.f, 0.f};

  // W fragment base: rows wave*32 + nj*16 + l15 of w1t slab (kq*256 rows total)
  const unsigned short* wl = w1t + ((size_t)wave * 32 + l15) * 8;

  // Load fragments for local chunk cl of super-phase sp (global chunk cg).
  auto ldfrags = [&](int cg, int cl, bf16x8* af, bf16x8* bfv) {
#pragma unroll
    for (int mi = 0; mi < 4; ++mi)
      af[mi] = *reinterpret_cast<const bf16x8*>(
          &smem[((cl * 4 + quad) * 64 + mi * 16 + l15) * 8]);
#pragma unroll
    for (int nj = 0; nj < 2; ++nj)
      bfv[nj] = *reinterpret_cast<const bf16x8*>(
          wl + (size_t)(cg * 4 + quad) * 2048 + nj * 128);
  };
  auto mm = [&](bf16x8* af, bf16x8* bfv) {
#pragma unroll
    for (int mi = 0; mi < 4; ++mi)
#pragma unroll
      for (int nj = 0; nj < 2; ++nj)
        acc[mi][nj] = __builtin_amdgcn_mfma_f32_16x16x32_bf16(
            af[mi], bfv[nj], acc[mi][nj], 0, 0, 0);
  };

  // One super-phase: stage X[64][416] (frag-major bf16) then 13 barrier-free
  // chunks with W ping-pong prefetch.
  auto superphase = [&](const int sp) {
    const int r  = tid >> 3;          // 0..63
    const int g0 = tid & 7;           // float4 group offset within row
    {  // batch 1: groups g0, g0+8, .., g0+48
      float4 xv[7];
#pragma unroll
      for (int it = 0; it < 7; ++it) {
        int g = g0 + it * 8;
        int col = sp * 416 + g * 4;
        if (col < 784)
          xv[it] = *reinterpret_cast<const float4*>(
              x + (size_t)(row0 + r) * 784 + col);
        else
          xv[it] = (float4){0.f, 0.f, 0.f, 0.f};
      }
#pragma unroll
      for (int it = 0; it < 7; ++it) {
        int g = g0 + it * 8;
        ushort4 b;
        b.x = f2bf(xv[it].x); b.y = f2bf(xv[it].y);
        b.z = f2bf(xv[it].z); b.w = f2bf(xv[it].w);
        *reinterpret_cast<ushort4*>(&smem[((g >> 1) * 64 + r) * 8 + (g & 1) * 4]) = b;
      }
    }
    {  // batch 2: groups g0+56, .., g0+96
      float4 xv[6];
#pragma unroll
      for (int it = 0; it < 6; ++it) {
        int g = g0 + 56 + it * 8;
        int col = sp * 416 + g * 4;
        if (col < 784)
          xv[it] = *reinterpret_cast<const float4*>(
              x + (size_t)(row0 + r) * 784 + col);
        else
          xv[it] = (float4){0.f, 0.f, 0.f, 0.f};
      }
#pragma unroll
      for (int it = 0; it < 6; ++it) {
        int g = g0 + 56 + it * 8;
        ushort4 b;
        b.x = f2bf(xv[it].x); b.y = f2bf(xv[it].y);
        b.z = f2bf(xv[it].z); b.w = f2bf(xv[it].w);
        *reinterpret_cast<ushort4*>(&smem[((g >> 1) * 64 + r) * 8 + (g & 1) * 4]) = b;
      }
    }
    __syncthreads();   // X ready

    bf16x8 afA[4], bfA[2], afB[4], bfB[2];
    ldfrags(sp * NCHP, 0, afA, bfA);
#pragma unroll
    for (int cl = 0; cl < NCHP; ++cl) {
      if ((cl & 1) == 0) {
        if (cl < NCHP - 1) ldfrags(sp * NCHP + cl + 1, cl + 1, afB, bfB);
        mm(afA, bfA);
      } else {
        if (cl < NCHP - 1) ldfrags(sp * NCHP + cl + 1, cl + 1, afA, bfA);
        mm(afB, bfB);
      }
    }
    __syncthreads();   // all waves done with this X before overwrite / overlay
  };

  superphase(0);
  superphase(1);

  // ---- epilogue layer 1: h = relu(a1*acc) -> Hs bf16 (overlays Xs) ----
  const float a1 = a1p[0];
  const float a2 = a2p[0];
#pragma unroll
  for (int mi = 0; mi < 4; ++mi) {
#pragma unroll
    for (int nj = 0; nj < 2; ++nj) {
      int col   = wave * 32 + nj * 16 + l15;
      int rbase = mi * 16 + quad * 4;
#pragma unroll
      for (int r = 0; r < 4; ++r) {
        float h = fmaxf(a1 * acc[mi][nj][r], 0.f);
        smem[(rbase + r) * HS_LD + col] = f2bf(h);
      }
    }
  }
  // ---- decode w2 -> W2s[16][264] (rows 10..15 zero) ----
  if (tid < 320) {
    int r = tid >> 5, j = tid & 31;
    unsigned int v = (unsigned int)w2p[r * 32 + j];
    unsigned int m = (unsigned int)m2p[r * 32 + j];
#pragma unroll
    for (int k = 0; k < 8; ++k) {
      unsigned int bit = (v >> (7 - k)) & 1u;
      unsigned int mk  = (m >> (7 - k)) & 1u;
      smem[OFF_W2 + r * W2_LD + j * 8 + k] =
          (unsigned short)(mk ? (bit ? 0x3F80u : 0xBF80u) : 0u);
    }
  }
  for (int idx = tid; idx < 6 * 256; idx += 512) {
    int r = 10 + (idx >> 8), c = idx & 255;
    smem[OFF_W2 + r * W2_LD + c] = 0;
  }
  __syncthreads();

  // ---- layer 2: out[64][10] = Hs @ W2s^T; waves 0..3, 16 rows each, K=256 ----
  if (wave < 4) {
    floatx4 o2 = (floatx4){0.f, 0.f, 0.f, 0.f};
#pragma unroll
    for (int ks = 0; ks < 8; ++ks) {
      bf16x8 ha = *reinterpret_cast<const bf16x8*>(
          &smem[(wave * 16 + l15) * HS_LD + ks * 32 + quad * 8]);
      bf16x8 wb = *reinterpret_cast<const bf16x8*>(
          &smem[OFF_W2 + l15 * W2_LD + ks * 32 + quad * 8]);
      o2 = __builtin_amdgcn_mfma_f32_16x16x32_bf16(ha, wb, o2, 0, 0, 0);
    }
    if (l15 < 10) {
#pragma unroll
      for (int r = 0; r < 4; ++r) {
        int gr = row0 + wave * 16 + quad * 4 + r;
        out[(size_t)gr * 10 + l15] = a2 * o2[r];
      }
    }
  }
}

extern "C" void kernel_launch(void* const* d_in, const int* in_sizes, int n_in,
                              void* d_out, int out_size, void* d_ws, size_t ws_size,
                              hipStream_t stream) {
  const float* x   = (const float*)d_in[0];
  const int*   w1p = (const int*)d_in[1];
  const int*   m1p = (const int*)d_in[2];
  const float* a1  = (const float*)d_in[3];
  const int*   w2p = (const int*)d_in[4];
  const int*   m2p = (const int*)d_in[5];
  const float* a2  = (const float*)d_in[6];
  unsigned short* w1t = (unsigned short*)d_ws;  // 104*256*8 bf16 = 416 KB scratch
  float* out = (float*)d_out;

  decode_w1_kernel<<<104, 256, 0, stream>>>(w1p, m1p, w1t);
  fused_kernel<<<512, 512, 0, stream>>>(x, w1t, w2p, m2p, a1, a2, out);
}